// Round 1
// baseline (3120.237 us; speedup 1.0000x reference)
//
#include <hip/hip_runtime.h>
#include <math.h>

// Problem constants (fixed by setup_inputs)
#define NS   2
#define NVIN 3
#define NVT  4
#define NC   16
#define ND   64
#define NH   96
#define NW   96
#define HWH  48          // half res h=w
#define SPR  64
#define DHW  (ND*NH*NW)  // 589824

// One wave (64 lanes) per ray; lane = depth sample index. Block = 256 = 4 rays.
__global__ __launch_bounds__(256) void render_kernel(
    const float* __restrict__ enc,
    const float* __restrict__ ipose,
    const float* __restrict__ tpose,
    const float* __restrict__ focal_p,
    const float* __restrict__ znear_p,
    const float* __restrict__ zfar_p,
    const float* __restrict__ W1, const float* __restrict__ B1,
    const float* __restrict__ W2, const float* __restrict__ B2,
    const float* __restrict__ W3, const float* __restrict__ B3,
    float* __restrict__ rhalf)
{
    const int lane = threadIdx.x & 63;
    const int ray  = blockIdx.x * 4 + (threadIdx.x >> 6);
    const int px   = ray % HWH;
    const int py   = (ray / HWH) % HWH;
    const int b    = ray / (HWH * HWH);   // b = s*NVT + t, in [0,8)
    const int s    = b >> 2;              // NVT = 4

    const float focal = focal_p[0];
    const float znear = znear_p[0];
    const float zfar  = zfar_p[0];

    // ---- ray generation (target pose is wave-uniform) ----
    const float* P = tpose + b * 16;
    float ysc = ((py + 0.5f) / (float)HWH) * 2.f - 1.f;
    float xsc = ((px + 0.5f) / (float)HWH) * 2.f - 1.f;
    float dcx = xsc / focal, dcy = -ysc / focal, dcz = -1.f;
    float dirx = P[0]*dcx + P[1]*dcy + P[2]*dcz;
    float diry = P[4]*dcx + P[5]*dcy + P[6]*dcz;
    float dirz = P[8]*dcx + P[9]*dcy + P[10]*dcz;
    float ox = P[3], oy = P[7], oz = P[11];

    float tv  = znear + (zfar - znear) * ((float)lane / (float)(SPR - 1));
    float ptx = ox + tv * dirx, pty = oy + tv * diry, ptz = oz + tv * dirz;

    float feats[NC];
    #pragma unroll
    for (int c = 0; c < NC; c++) feats[c] = 0.f;

    const float minz = focal * znear, maxz = focal * zfar;

    // ---- 3-view trilinear gather ----
    for (int v = 0; v < NVIN; v++) {
        const float* E = ipose + (s * NVIN + v) * 16;
        float qx = ptx - E[3], qy = pty - E[7], qz = ptz - E[11];
        // local = R^T (pt - tr); R[j][i] = E[j*4+i]
        float lx = E[0]*qx + E[4]*qy + E[8]*qz;
        float ly = E[1]*qx + E[5]*qy + E[9]*qz;
        float lz = E[2]*qx + E[6]*qy + E[10]*qz;
        float zz = -lz;
        float u  = lx / zz * focal;
        float vv = ly / zz * focal;
        float wd = 2.f * (zz - minz) / (maxz - minz) - 1.f;
        float gx = u, gy = -vv, gz = -wd;
        float ix = ((gx + 1.f) * NW - 1.f) * 0.5f;
        float iy = ((gy + 1.f) * NH - 1.f) * 0.5f;
        float iz = ((gz + 1.f) * ND - 1.f) * 0.5f;
        float x0 = floorf(ix), y0 = floorf(iy), z0 = floorf(iz);

        float wgt[8]; int idx[8];
        #pragma unroll
        for (int k = 0; k < 8; k++) {
            float xc = x0 + (k & 1), yc = y0 + ((k >> 1) & 1), zc = z0 + (k >> 2);
            float wt = (1.f - fabsf(ix - xc)) * (1.f - fabsf(iy - yc)) * (1.f - fabsf(iz - zc));
            bool valid = (xc >= 0.f) && (xc < (float)NW) &&
                         (yc >= 0.f) && (yc < (float)NH) &&
                         (zc >= 0.f) && (zc < (float)ND);
            wgt[k] = valid ? wt : 0.f;
            int xi = min(max((int)xc, 0), NW - 1);
            int yi = min(max((int)yc, 0), NH - 1);
            int zi = min(max((int)zc, 0), ND - 1);
            idx[k] = (zi * NH + yi) * NW + xi;
        }
        const float* VB = enc + (size_t)(s * NVIN + v) * NC * DHW;
        #pragma unroll
        for (int c = 0; c < NC; c++) {
            const float* vc = VB + c * DHW;
            float acc = 0.f;
            #pragma unroll
            for (int k = 0; k < 8; k++) acc += wgt[k] * vc[idx[k]];
            feats[c] += acc;
        }
    }
    #pragma unroll
    for (int c = 0; c < NC; c++) feats[c] *= (1.f / 3.f);

    // ---- MLP (weights wave-uniform -> s_load + v_fmac) ----
    float h1[64];
    #pragma unroll
    for (int j = 0; j < 64; j++) {
        float a = B1[j];
        #pragma unroll
        for (int i = 0; i < NC; i++) a += feats[i] * W1[i * 64 + j];
        h1[j] = fmaxf(a, 0.f);
    }
    float h2[64];
    #pragma unroll
    for (int k = 0; k < 64; k++) {
        float a = B2[k];
        #pragma unroll
        for (int j = 0; j < 64; j++) a += h1[j] * W2[j * 64 + k];
        h2[k] = fmaxf(a, 0.f);
    }
    float o0 = B3[0];
    #pragma unroll
    for (int k = 0; k < 64; k++) o0 += h2[k] * W3[k * 17 + 0];
    float density = fmaxf(o0, 0.f);

    float rgb[NC];
    #pragma unroll
    for (int c = 0; c < NC; c++) {
        float a = B3[1 + c];
        #pragma unroll
        for (int k = 0; k < 64; k++) a += h2[k] * W3[k * 17 + 1 + c];
        rgb[c] = feats[c] + a;
    }

    // ---- per-ray compositing (wave = ray) ----
    float tn = znear + (zfar - znear) * ((float)(lane + 1) / (float)(SPR - 1));
    float delta = (lane < SPR - 1) ? (tn - tv) : 1e10f;
    float sigdel = density * delta;
    float alpha = 1.f - expf(-sigdel);
    float csum = sigdel;            // inclusive prefix sum (matches jnp.cumsum)
    #pragma unroll
    for (int off = 1; off < 64; off <<= 1) {
        float nb = __shfl_up(csum, off, 64);
        if (lane >= off) csum += nb;
    }
    float wray = alpha * expf(-csum);

    #pragma unroll
    for (int c = 0; c < NC; c++) {
        float val = wray * rgb[c];
        #pragma unroll
        for (int off = 32; off >= 1; off >>= 1)
            val += __shfl_down(val, off, 64);
        if (lane == 0)
            rhalf[((b * NC + c) * HWH + py) * HWH + px] = val;
    }
}

// 2x bilinear upsample, align_corners=True. One thread per output element.
__global__ __launch_bounds__(256) void upsample_kernel(
    const float* __restrict__ in, float* __restrict__ out)
{
    int tid = blockIdx.x * 256 + threadIdx.x;
    int ox = tid % NW;
    int oy = (tid / NW) % NH;
    int c  = (tid / (NW * NH)) % NC;
    int b  = tid / (NW * NH * NC);
    const float sc = (float)((HWH - 1) / (double)(NH - 1)); // 47/95
    float pyf = oy * sc;
    float pxf = ox * sc;
    int y0 = (int)floorf(pyf); int y1 = min(y0 + 1, HWH - 1); float fy = pyf - y0;
    int x0 = (int)floorf(pxf); int x1 = min(x0 + 1, HWH - 1); float fx = pxf - x0;
    const float* src = in + (b * NC + c) * HWH * HWH;
    float v00 = src[y0 * HWH + x0], v01 = src[y0 * HWH + x1];
    float v10 = src[y1 * HWH + x0], v11 = src[y1 * HWH + x1];
    float gl = v00 * (1.f - fy) + v10 * fy;   // y-interp at x0
    float gr = v01 * (1.f - fy) + v11 * fy;   // y-interp at x1
    out[tid] = gl * (1.f - fx) + gr * fx;
}

extern "C" void kernel_launch(void* const* d_in, const int* in_sizes, int n_in,
                              void* d_out, int out_size, void* d_ws, size_t ws_size,
                              hipStream_t stream) {
    const float* enc   = (const float*)d_in[0];
    const float* ipose = (const float*)d_in[1];
    const float* tpose = (const float*)d_in[2];
    const float* focal = (const float*)d_in[3];
    const float* znear = (const float*)d_in[4];
    const float* zfar  = (const float*)d_in[5];
    // d_in[6] = samples_per_ray (int, fixed 64 — hard-coded as SPR)
    const float* W1 = (const float*)d_in[7];
    const float* B1 = (const float*)d_in[8];
    const float* W2 = (const float*)d_in[9];
    const float* B2 = (const float*)d_in[10];
    const float* W3 = (const float*)d_in[11];
    const float* B3 = (const float*)d_in[12];

    float* rhalf = (float*)d_ws;   // 8*16*48*48 floats = 1.18 MB
    float* out   = (float*)d_out;

    const int nrays = NS * NVT * HWH * HWH;        // 18432
    render_kernel<<<nrays / 4, 256, 0, stream>>>(
        enc, ipose, tpose, focal, znear, zfar,
        W1, B1, W2, B2, W3, B3, rhalf);

    const int nout = NS * NVT * NC * NH * NW;      // 1179648
    upsample_kernel<<<nout / 256, 256, 0, stream>>>(rhalf, out);
}

// Round 2
// 774.577 us; speedup vs baseline: 4.0283x; 4.0283x over previous
//
#include <hip/hip_runtime.h>
#include <math.h>

// Problem constants (fixed by setup_inputs)
#define NS   2
#define NVIN 3
#define NVT  4
#define NC   16
#define ND   64
#define NH   96
#define NW   96
#define HWH  48          // half res h=w
#define SPR  64
#define DHW  (ND*NH*NW)  // 589824

// ---------------------------------------------------------------------------
// Transpose enc [6][16][DHW] -> enc_t [6][DHW][16]  (channel-last, 64B/voxel)
// One thread per output float4: tid = sv*DHW*4 + vox*4 + c4. Writes fully
// coalesced; reads are 4 streams of 16-lane-contiguous dwords.
// ---------------------------------------------------------------------------
__global__ __launch_bounds__(256) void transpose_kernel(
    const float* __restrict__ in, float* __restrict__ out)
{
    int tid = blockIdx.x * 256 + threadIdx.x;    // 6*DHW*4 total
    int c4  = tid & 3;
    int vox = (tid >> 2) % DHW;
    int sv  = tid / (4 * DHW);
    const float* src = in + ((size_t)sv * NC + c4 * 4) * DHW + vox;
    float4 v = make_float4(src[0], src[DHW], src[2 * DHW], src[3 * DHW]);
    ((float4*)out)[tid] = v;
}

// ---------------------------------------------------------------------------
// Fused render, channel-last gather. One wave per ray, lane = depth sample.
// ---------------------------------------------------------------------------
__global__ __launch_bounds__(256, 4) void render_cl_kernel(
    const float* __restrict__ enc_t,
    const float* __restrict__ ipose,
    const float* __restrict__ tpose,
    const float* __restrict__ focal_p,
    const float* __restrict__ znear_p,
    const float* __restrict__ zfar_p,
    const float* __restrict__ W1, const float* __restrict__ B1,
    const float* __restrict__ W2, const float* __restrict__ B2,
    const float* __restrict__ W3, const float* __restrict__ B3,
    float* __restrict__ rhalf)
{
    const int lane = threadIdx.x & 63;
    const int ray  = blockIdx.x * 4 + (threadIdx.x >> 6);
    const int px   = ray % HWH;
    const int py   = (ray / HWH) % HWH;
    const int b    = ray / (HWH * HWH);   // s*NVT + t
    const int s    = b >> 2;

    const float focal = focal_p[0];
    const float znear = znear_p[0];
    const float zfar  = zfar_p[0];

    // ---- ray generation ----
    const float* P = tpose + b * 16;
    float ysc = ((py + 0.5f) / (float)HWH) * 2.f - 1.f;
    float xsc = ((px + 0.5f) / (float)HWH) * 2.f - 1.f;
    float dcx = xsc / focal, dcy = -ysc / focal, dcz = -1.f;
    float dirx = P[0]*dcx + P[1]*dcy + P[2]*dcz;
    float diry = P[4]*dcx + P[5]*dcy + P[6]*dcz;
    float dirz = P[8]*dcx + P[9]*dcy + P[10]*dcz;
    float ox = P[3], oy = P[7], oz = P[11];

    float tv  = znear + (zfar - znear) * ((float)lane / (float)(SPR - 1));
    float ptx = ox + tv * dirx, pty = oy + tv * diry, ptz = oz + tv * dirz;

    float feats[NC];
    #pragma unroll
    for (int c = 0; c < NC; c++) feats[c] = 0.f;

    const float minz = focal * znear, maxz = focal * zfar;

    // ---- 3-view trilinear gather (channel-last: 64B per corner) ----
    for (int v = 0; v < NVIN; v++) {
        const float* E = ipose + (s * NVIN + v) * 16;
        float qx = ptx - E[3], qy = pty - E[7], qz = ptz - E[11];
        float lx = E[0]*qx + E[4]*qy + E[8]*qz;
        float ly = E[1]*qx + E[5]*qy + E[9]*qz;
        float lz = E[2]*qx + E[6]*qy + E[10]*qz;
        float zz = -lz;
        float u  = lx / zz * focal;
        float vv = ly / zz * focal;
        float wd = 2.f * (zz - minz) / (maxz - minz) - 1.f;
        float ix = ((u   + 1.f) * NW - 1.f) * 0.5f;
        float iy = ((-vv + 1.f) * NH - 1.f) * 0.5f;
        float iz = ((-wd + 1.f) * ND - 1.f) * 0.5f;
        float x0 = floorf(ix), y0 = floorf(iy), z0 = floorf(iz);

        float wgt[8]; int idx[8];
        #pragma unroll
        for (int k = 0; k < 8; k++) {
            float xc = x0 + (k & 1), yc = y0 + ((k >> 1) & 1), zc = z0 + (k >> 2);
            float wt = (1.f - fabsf(ix - xc)) * (1.f - fabsf(iy - yc)) * (1.f - fabsf(iz - zc));
            bool valid = (xc >= 0.f) && (xc < (float)NW) &&
                         (yc >= 0.f) && (yc < (float)NH) &&
                         (zc >= 0.f) && (zc < (float)ND);
            wgt[k] = valid ? wt : 0.f;
            int xi = min(max((int)xc, 0), NW - 1);
            int yi = min(max((int)yc, 0), NH - 1);
            int zi = min(max((int)zc, 0), ND - 1);
            idx[k] = (zi * NH + yi) * NW + xi;
        }
        const float* VB = enc_t + (size_t)(s * NVIN + v) * DHW * NC;
        #pragma unroll
        for (int k = 0; k < 8; k++) {
            const float* p = VB + (size_t)idx[k] * NC;
            float4 a0 = *(const float4*)(p);
            float4 a1 = *(const float4*)(p + 4);
            float4 a2 = *(const float4*)(p + 8);
            float4 a3 = *(const float4*)(p + 12);
            float w = wgt[k];
            feats[0]  += w * a0.x; feats[1]  += w * a0.y;
            feats[2]  += w * a0.z; feats[3]  += w * a0.w;
            feats[4]  += w * a1.x; feats[5]  += w * a1.y;
            feats[6]  += w * a1.z; feats[7]  += w * a1.w;
            feats[8]  += w * a2.x; feats[9]  += w * a2.y;
            feats[10] += w * a2.z; feats[11] += w * a2.w;
            feats[12] += w * a3.x; feats[13] += w * a3.y;
            feats[14] += w * a3.z; feats[15] += w * a3.w;
        }
    }
    #pragma unroll
    for (int c = 0; c < NC; c++) feats[c] *= (1.f / 3.f);

    // ---- fused MLP: layer1 streamed into layer2 accumulators ----
    float h2a[64];
    #pragma unroll
    for (int k = 0; k < 64; k++) h2a[k] = B2[k];
    #pragma unroll 4
    for (int j = 0; j < 64; j++) {
        float a = B1[j];
        #pragma unroll
        for (int i = 0; i < NC; i++) a += feats[i] * W1[i * 64 + j];
        a = fmaxf(a, 0.f);
        #pragma unroll
        for (int k = 0; k < 64; k++) h2a[k] += a * W2[j * 64 + k];
    }
    float outa[17];
    #pragma unroll
    for (int c = 0; c < 17; c++) outa[c] = B3[c];
    #pragma unroll 4
    for (int k = 0; k < 64; k++) {
        float hv = fmaxf(h2a[k], 0.f);
        #pragma unroll
        for (int c = 0; c < 17; c++) outa[c] += hv * W3[k * 17 + c];
    }
    float density = fmaxf(outa[0], 0.f);

    // ---- per-ray compositing ----
    float tn = znear + (zfar - znear) * ((float)(lane + 1) / (float)(SPR - 1));
    float delta = (lane < SPR - 1) ? (tn - tv) : 1e10f;
    float sigdel = density * delta;
    float alpha = 1.f - expf(-sigdel);
    float csum = sigdel;
    #pragma unroll
    for (int off = 1; off < 64; off <<= 1) {
        float nb = __shfl_up(csum, off, 64);
        if (lane >= off) csum += nb;
    }
    float wray = alpha * expf(-csum);

    #pragma unroll
    for (int c = 0; c < NC; c++) {
        float val = wray * (feats[c] + outa[1 + c]);
        #pragma unroll
        for (int off = 32; off >= 1; off >>= 1)
            val += __shfl_down(val, off, 64);
        if (lane == 0)
            rhalf[((b * NC + c) * HWH + py) * HWH + px] = val;
    }
}

// ---------------------------------------------------------------------------
// Fallback render (R1-proven, channel-first) — used only if ws too small.
// ---------------------------------------------------------------------------
__global__ __launch_bounds__(256) void render_kernel(
    const float* __restrict__ enc,
    const float* __restrict__ ipose,
    const float* __restrict__ tpose,
    const float* __restrict__ focal_p,
    const float* __restrict__ znear_p,
    const float* __restrict__ zfar_p,
    const float* __restrict__ W1, const float* __restrict__ B1,
    const float* __restrict__ W2, const float* __restrict__ B2,
    const float* __restrict__ W3, const float* __restrict__ B3,
    float* __restrict__ rhalf)
{
    const int lane = threadIdx.x & 63;
    const int ray  = blockIdx.x * 4 + (threadIdx.x >> 6);
    const int px   = ray % HWH;
    const int py   = (ray / HWH) % HWH;
    const int b    = ray / (HWH * HWH);
    const int s    = b >> 2;

    const float focal = focal_p[0];
    const float znear = znear_p[0];
    const float zfar  = zfar_p[0];

    const float* P = tpose + b * 16;
    float ysc = ((py + 0.5f) / (float)HWH) * 2.f - 1.f;
    float xsc = ((px + 0.5f) / (float)HWH) * 2.f - 1.f;
    float dcx = xsc / focal, dcy = -ysc / focal, dcz = -1.f;
    float dirx = P[0]*dcx + P[1]*dcy + P[2]*dcz;
    float diry = P[4]*dcx + P[5]*dcy + P[6]*dcz;
    float dirz = P[8]*dcx + P[9]*dcy + P[10]*dcz;
    float ox = P[3], oy = P[7], oz = P[11];

    float tv  = znear + (zfar - znear) * ((float)lane / (float)(SPR - 1));
    float ptx = ox + tv * dirx, pty = oy + tv * diry, ptz = oz + tv * dirz;

    float feats[NC];
    #pragma unroll
    for (int c = 0; c < NC; c++) feats[c] = 0.f;

    const float minz = focal * znear, maxz = focal * zfar;

    for (int v = 0; v < NVIN; v++) {
        const float* E = ipose + (s * NVIN + v) * 16;
        float qx = ptx - E[3], qy = pty - E[7], qz = ptz - E[11];
        float lx = E[0]*qx + E[4]*qy + E[8]*qz;
        float ly = E[1]*qx + E[5]*qy + E[9]*qz;
        float lz = E[2]*qx + E[6]*qy + E[10]*qz;
        float zz = -lz;
        float u  = lx / zz * focal;
        float vv = ly / zz * focal;
        float wd = 2.f * (zz - minz) / (maxz - minz) - 1.f;
        float ix = ((u   + 1.f) * NW - 1.f) * 0.5f;
        float iy = ((-vv + 1.f) * NH - 1.f) * 0.5f;
        float iz = ((-wd + 1.f) * ND - 1.f) * 0.5f;
        float x0 = floorf(ix), y0 = floorf(iy), z0 = floorf(iz);

        float wgt[8]; int idx[8];
        #pragma unroll
        for (int k = 0; k < 8; k++) {
            float xc = x0 + (k & 1), yc = y0 + ((k >> 1) & 1), zc = z0 + (k >> 2);
            float wt = (1.f - fabsf(ix - xc)) * (1.f - fabsf(iy - yc)) * (1.f - fabsf(iz - zc));
            bool valid = (xc >= 0.f) && (xc < (float)NW) &&
                         (yc >= 0.f) && (yc < (float)NH) &&
                         (zc >= 0.f) && (zc < (float)ND);
            wgt[k] = valid ? wt : 0.f;
            int xi = min(max((int)xc, 0), NW - 1);
            int yi = min(max((int)yc, 0), NH - 1);
            int zi = min(max((int)zc, 0), ND - 1);
            idx[k] = (zi * NH + yi) * NW + xi;
        }
        const float* VB = enc + (size_t)(s * NVIN + v) * NC * DHW;
        #pragma unroll
        for (int c = 0; c < NC; c++) {
            const float* vc = VB + c * DHW;
            float acc = 0.f;
            #pragma unroll
            for (int k = 0; k < 8; k++) acc += wgt[k] * vc[idx[k]];
            feats[c] += acc;
        }
    }
    #pragma unroll
    for (int c = 0; c < NC; c++) feats[c] *= (1.f / 3.f);

    float h2a[64];
    #pragma unroll
    for (int k = 0; k < 64; k++) h2a[k] = B2[k];
    #pragma unroll 4
    for (int j = 0; j < 64; j++) {
        float a = B1[j];
        #pragma unroll
        for (int i = 0; i < NC; i++) a += feats[i] * W1[i * 64 + j];
        a = fmaxf(a, 0.f);
        #pragma unroll
        for (int k = 0; k < 64; k++) h2a[k] += a * W2[j * 64 + k];
    }
    float outa[17];
    #pragma unroll
    for (int c = 0; c < 17; c++) outa[c] = B3[c];
    #pragma unroll 4
    for (int k = 0; k < 64; k++) {
        float hv = fmaxf(h2a[k], 0.f);
        #pragma unroll
        for (int c = 0; c < 17; c++) outa[c] += hv * W3[k * 17 + c];
    }
    float density = fmaxf(outa[0], 0.f);

    float tn = znear + (zfar - znear) * ((float)(lane + 1) / (float)(SPR - 1));
    float delta = (lane < SPR - 1) ? (tn - tv) : 1e10f;
    float sigdel = density * delta;
    float alpha = 1.f - expf(-sigdel);
    float csum = sigdel;
    #pragma unroll
    for (int off = 1; off < 64; off <<= 1) {
        float nb = __shfl_up(csum, off, 64);
        if (lane >= off) csum += nb;
    }
    float wray = alpha * expf(-csum);

    #pragma unroll
    for (int c = 0; c < NC; c++) {
        float val = wray * (feats[c] + outa[1 + c]);
        #pragma unroll
        for (int off = 32; off >= 1; off >>= 1)
            val += __shfl_down(val, off, 64);
        if (lane == 0)
            rhalf[((b * NC + c) * HWH + py) * HWH + px] = val;
    }
}

// 2x bilinear upsample, align_corners=True.
__global__ __launch_bounds__(256) void upsample_kernel(
    const float* __restrict__ in, float* __restrict__ out)
{
    int tid = blockIdx.x * 256 + threadIdx.x;
    int ox = tid % NW;
    int oy = (tid / NW) % NH;
    int c  = (tid / (NW * NH)) % NC;
    int b  = tid / (NW * NH * NC);
    const float sc = (float)((HWH - 1) / (double)(NH - 1)); // 47/95
    float pyf = oy * sc;
    float pxf = ox * sc;
    int y0 = (int)floorf(pyf); int y1 = min(y0 + 1, HWH - 1); float fy = pyf - y0;
    int x0 = (int)floorf(pxf); int x1 = min(x0 + 1, HWH - 1); float fx = pxf - x0;
    const float* src = in + (b * NC + c) * HWH * HWH;
    float v00 = src[y0 * HWH + x0], v01 = src[y0 * HWH + x1];
    float v10 = src[y1 * HWH + x0], v11 = src[y1 * HWH + x1];
    float gl = v00 * (1.f - fy) + v10 * fy;
    float gr = v01 * (1.f - fy) + v11 * fy;
    out[tid] = gl * (1.f - fx) + gr * fx;
}

extern "C" void kernel_launch(void* const* d_in, const int* in_sizes, int n_in,
                              void* d_out, int out_size, void* d_ws, size_t ws_size,
                              hipStream_t stream) {
    const float* enc   = (const float*)d_in[0];
    const float* ipose = (const float*)d_in[1];
    const float* tpose = (const float*)d_in[2];
    const float* focal = (const float*)d_in[3];
    const float* znear = (const float*)d_in[4];
    const float* zfar  = (const float*)d_in[5];
    const float* W1 = (const float*)d_in[7];
    const float* B1 = (const float*)d_in[8];
    const float* W2 = (const float*)d_in[9];
    const float* B2 = (const float*)d_in[10];
    const float* W3 = (const float*)d_in[11];
    const float* B3 = (const float*)d_in[12];

    float* out = (float*)d_out;
    const int nrays = NS * NVT * HWH * HWH;              // 18432
    const int nout  = NS * NVT * NC * NH * NW;           // 1179648
    const size_t enc_t_bytes = (size_t)NS * NVIN * NC * DHW * 4;   // 226.5 MB
    const size_t rhalf_bytes = (size_t)NS * NVT * NC * HWH * HWH * 4;

    if (ws_size >= enc_t_bytes + rhalf_bytes) {
        float* enc_t = (float*)d_ws;
        float* rhalf = (float*)((char*)d_ws + enc_t_bytes);
        const int ntrans = NS * NVIN * DHW * 4;          // float4 count
        transpose_kernel<<<ntrans / 256, 256, 0, stream>>>(enc, enc_t);
        render_cl_kernel<<<nrays / 4, 256, 0, stream>>>(
            enc_t, ipose, tpose, focal, znear, zfar,
            W1, B1, W2, B2, W3, B3, rhalf);
        upsample_kernel<<<nout / 256, 256, 0, stream>>>(rhalf, out);
    } else {
        float* rhalf = (float*)d_ws;
        render_kernel<<<nrays / 4, 256, 0, stream>>>(
            enc, ipose, tpose, focal, znear, zfar,
            W1, B1, W2, B2, W3, B3, rhalf);
        upsample_kernel<<<nout / 256, 256, 0, stream>>>(rhalf, out);
    }
}